// Round 5
// baseline (200.759 us; speedup 1.0000x reference)
//
#include <hip/hip_runtime.h>
#include <hip/hip_bf16.h>

#define LN 96
#define BN 32
#define DM 128
#define EPN 95   // edges per receiver = L-1

typedef __attribute__((ext_vector_type(8))) short s16x8;
typedef __attribute__((ext_vector_type(4))) float f32x4;

__device__ __forceinline__ float eluf(float x){ return x > 0.f ? x : __expf(x) - 1.f; }
__device__ __forceinline__ unsigned short f2bf(float f){
    unsigned u = __float_as_uint(f);
    return (unsigned short)((u + 0x7fff + ((u >> 16) & 1)) >> 16);
}
__device__ __forceinline__ float bf2f(unsigned short h){ return __uint_as_float(((unsigned)h) << 16); }

// ---------------- weight pack: 19 slots, fragment-order bf16 hi+lo ----------------
// chunk c=(nt*4+ks)*64+lane holds 8 elems: n = nt*16+(lane&15), k = ks*32+(lane>>4)*8+e
// slots: 0..2 eW2[i]; 3 W0b; 4,5 eW1[0] S/R; 6 nW1[0]; 7 nW2[0]; 8,9 eW1[1] S/R;
//        10 nW1[1]; 11 nW2[1]; 12,13 eW1[2] S/R; 14 nW1[2]; 15 nW2[2]; 16,17 fW1 S/R;
//        18 fW2 (128x6 zero-padded to 128x16)
struct SrcTab { const float* p[19]; };

__global__ void conv_pack_kernel(SrcTab tab, unsigned short* __restrict__ hi,
                                 unsigned short* __restrict__ lo){
    int tid = blockIdx.x * 256 + threadIdx.x;   // 19*2048 = 38912
    int m = tid >> 11, c = tid & 2047;
    int l = c & 63, f = c >> 6;
    int n = (f >> 2) * 16 + (l & 15);
    int k0 = (f & 3) * 32 + (l >> 4) * 8;
    union { unsigned short us[8]; uint4 v; } ph, pl;
#pragma unroll
    for (int e = 0; e < 8; ++e){
        float x;
        if (m == 18) x = (n < 6) ? tab.p[18][(k0 + e) * 6 + n] : 0.f;
        else         x = tab.p[m][(k0 + e) * DM + n];
        unsigned short h = f2bf(x);
        ph.us[e] = h;
        pl.us[e] = f2bf(x - bf2f(h));
    }
    *(uint4*)(hi + (size_t)tid * 8) = ph.v;
    *(uint4*)(lo + (size_t)tid * 8) = pl.v;
}

__device__ __forceinline__ const s16x8* frag(const unsigned short* w, int wv, int ks, int l){
    return (const s16x8*)(w + (size_t)(((wv * 4 + ks) * 64) + l) * 8);
}

// wave-level 16-row x 16-col matmul over K=128, hi+lo weights
__device__ __forceinline__ f32x4 nmm(const char* aT, int l, int wv,
        const unsigned short* __restrict__ wh, const unsigned short* __restrict__ wl, float bias){
    const int l15 = l & 15, kgrp = l >> 4;
    const char* rb = aT + l15 * 256;
    const int swz = (l15 & 7) << 4;
    s16x8 a[4];
#pragma unroll
    for (int ks = 0; ks < 4; ++ks)
        a[ks] = *(const s16x8*)(rb + (((ks * 32 + kgrp * 8) * 2) ^ swz));
    f32x4 acc = (f32x4){bias, bias, bias, bias};
#pragma unroll
    for (int ks = 0; ks < 4; ++ks)
        acc = __builtin_amdgcn_mfma_f32_16x16x32_bf16(a[ks], *frag(wh, wv, ks, l), acc, 0, 0, 0);
#pragma unroll
    for (int ks = 0; ks < 4; ++ks)
        acc = __builtin_amdgcn_mfma_f32_16x16x32_bf16(a[ks], *frag(wl, wv, ks, l), acc, 0, 0, 0);
    return acc;
}

__device__ __forceinline__ void store_act(char* dT, int l, int wv, f32x4 acc){
    const int l15 = l & 15, kgrp = l >> 4;
    const int col = wv * 16 + l15;
#pragma unroll
    for (int i = 0; i < 4; ++i){
        int row = kgrp * 4 + i;   // C/D: col=lane&15, row=(lane>>4)*4+i
        *(unsigned short*)(dT + ((row * 256 + col * 2) ^ ((row & 7) << 4))) = f2bf(eluf(acc[i]));
    }
}

// ---------------- persistent kernel: whole network; 8 blocks per batch ----------------
__global__ __launch_bounds__(512, 1) void gnn_persistent(
    const float* __restrict__ in,
    const float* __restrict__ W0a, const float* __restrict__ b0a, const float* __restrict__ b0b,
    const float* __restrict__ nb1, const float* __restrict__ nb2,
    const float* __restrict__ eb1, const float* __restrict__ eb2,
    const float* __restrict__ fb1, const float* __restrict__ fb2,
    const unsigned short* __restrict__ whi, const unsigned short* __restrict__ wlo,
    float* __restrict__ hsbuf, unsigned* __restrict__ ctr,
    float* __restrict__ out){

    __shared__ float hsL[LN * 132];     // senders (f32), padded stride
    __shared__ float hrL[12 * DM];      // own hr rows
    __shared__ float gL[12 * DM];       // own g rows (edge out / node in)
    __shared__ char actA[16 * 256];     // node A-tiles (bf16, XOR-swizzled)
    __shared__ char actB[16 * 256];
    __shared__ char y1[LN * 256];       // edge A-tile

    const int blk = blockIdx.x;
    const int bb = blk >> 3, p = blk & 7;
    const int r0 = p * 12;              // this block's 12 node rows == its 12 receivers
    const int t = threadIdx.x;
    const int wv = t >> 6, l = t & 63;
    const int l15 = l & 15, kgrp = l >> 4;
    unsigned* ctrb = ctr + bb * 32;     // padded counter per batch

    for (int it = 0; it < 4; ++it){
        // ---------- node stage: stage A-tile (12 real rows, 4 pad) ----------
        {
            int rr = t >> 5, q = t & 31, c0 = q * 4;
            int swz = (rr & 7) << 4;
            union { unsigned short us[4]; ushort4 v; } pk;
            pk.us[0] = pk.us[1] = pk.us[2] = pk.us[3] = 0;
            if (rr < 12){
                if (it == 0){
                    int ll = r0 + rr;
                    float4 x = *(const float4*)(in + (size_t)(ll * BN + bb) * 4);
#pragma unroll
                    for (int j = 0; j < 4; ++j){
                        int c = c0 + j;
                        float a = b0a[c] + x.x * W0a[c] + x.y * W0a[DM + c]
                                + x.z * W0a[2 * DM + c] + x.w * W0a[3 * DM + c];
                        pk.us[j] = f2bf(eluf(a));
                    }
                } else {
                    float4 v = *(const float4*)(gL + rr * DM + c0);
                    pk.us[0] = f2bf(v.x); pk.us[1] = f2bf(v.y);
                    pk.us[2] = f2bf(v.z); pk.us[3] = f2bf(v.w);
                }
            }
            *(ushort4*)(actA + ((rr * 256 + c0 * 2) ^ swz)) = pk.v;
        }
        __syncthreads();

        const int sL2 = (it == 0) ? 3 : (it == 1) ? 7 : (it == 2) ? 11 : 15;
        const int sS  = (it == 0) ? 4 : (it == 1) ? 8 : (it == 2) ? 12 : 16;
        const float* bL2 = (it == 0) ? b0b : (it == 1) ? nb2 : (it == 2) ? nb2 + DM : nb2 + 2 * DM;
        const float* bP  = (it == 0) ? eb1 : (it == 1) ? eb1 + DM : (it == 2) ? eb1 + 2 * DM : fb1;

        const char* srcA;
        if (it > 0){
            const int sL1 = (it == 1) ? 6 : (it == 2) ? 10 : 14;
            const float* bL1 = (it == 1) ? nb1 : (it == 2) ? nb1 + DM : nb1 + 2 * DM;
            f32x4 acc = nmm(actA, l, wv, whi + sL1 * 16384, wlo + sL1 * 16384, bL1[wv * 16 + l15]);
            store_act(actB, l, wv, acc);
            __syncthreads();
            acc = nmm(actB, l, wv, whi + sL2 * 16384, wlo + sL2 * 16384, bL2[wv * 16 + l15]);
            store_act(actA, l, wv, acc);   // all actA reads finished before previous sync
            __syncthreads();
            srcA = actA;
        } else {
            f32x4 acc = nmm(actA, l, wv, whi + sL2 * 16384, wlo + sL2 * 16384, bL2[wv * 16 + l15]);
            store_act(actB, l, wv, acc);
            __syncthreads();
            srcA = actB;
        }

        float* hsP = hsbuf + (size_t)(it & 1) * (BN * LN * DM) + (size_t)(bb * LN) * DM;
        {
            f32x4 acc = nmm(srcA, l, wv, whi + sS * 16384, wlo + sS * 16384, 0.f);
#pragma unroll
            for (int i = 0; i < 4; ++i){
                int row = kgrp * 4 + i;
                if (row < 12) hsP[(size_t)(r0 + row) * DM + wv * 16 + l15] = acc[i];
            }
            acc = nmm(srcA, l, wv, whi + (sS + 1) * 16384, wlo + (sS + 1) * 16384, bP[wv * 16 + l15]);
#pragma unroll
            for (int i = 0; i < 4; ++i){
                int row = kgrp * 4 + i;
                if (row < 12) hrL[row * DM + wv * 16 + l15] = acc[i];
            }
        }

        // ---------- per-batch barrier (canonical release/acquire; all blocks resident) ----------
        __syncthreads();
        if (t == 0){
            __threadfence();
            __hip_atomic_fetch_add(ctrb, 1u, __ATOMIC_RELEASE, __HIP_MEMORY_SCOPE_AGENT);
            unsigned tgt = 8u * (unsigned)(it + 1);
            while (__hip_atomic_load(ctrb, __ATOMIC_ACQUIRE, __HIP_MEMORY_SCOPE_AGENT) < tgt)
                __builtin_amdgcn_s_sleep(2);
            __threadfence();
        }
        __syncthreads();

        // ---------- stage all 96 hs rows of this batch into LDS ----------
#pragma unroll
        for (int rep = 0; rep < 6; ++rep){
            int task = t + rep * 512;
            int rr = task >> 5, c4 = (task & 31) * 4;
            *(float4*)(hsL + rr * 132 + c4) = *(const float4*)(hsP + (size_t)rr * DM + c4);
        }

        auto buildY1 = [&](int r, int r12){
#pragma unroll
            for (int rep = 0; rep < 3; ++rep){
                int task = t + rep * 512;
                int rr = task >> 4, c0 = (task & 15) * 8;
                int swz = (rr & 7) << 4;
                union { unsigned short us[8]; uint4 v; } pk;
                if (rr < EPN){
                    int j = rr + (rr >= r);
                    const float* hp = hsL + j * 132 + c0;
                    const float* rp = hrL + r12 * DM + c0;
                    f32x4 h0 = *(const f32x4*)hp, h1 = *(const f32x4*)(hp + 4);
                    f32x4 v0 = *(const f32x4*)rp, v1 = *(const f32x4*)(rp + 4);
#pragma unroll
                    for (int e = 0; e < 4; ++e){
                        pk.us[e]     = f2bf(eluf(h0[e] + v0[e]));
                        pk.us[e + 4] = f2bf(eluf(h1[e] + v1[e]));
                    }
                } else pk.v = make_uint4(0, 0, 0, 0);
                *(uint4*)(y1 + ((rr * 256 + c0 * 2) ^ swz)) = pk.v;
            }
        };

        if (it < 3){
            // ---------- edge stage: 12 receivers, B-frags in regs ----------
            s16x8 bfr[4];
#pragma unroll
            for (int ks = 0; ks < 4; ++ks) bfr[ks] = *frag(whi + it * 16384, wv, ks, l);
            float b2v = eb2[it * DM + wv * 16 + l15];
            __syncthreads();
            for (int r12 = 0; r12 < 12; ++r12){
                buildY1(r0 + r12, r12);
                __syncthreads();
                f32x4 a6[6];
#pragma unroll
                for (int mt = 0; mt < 6; ++mt){
                    int arow = mt * 16 + l15;
                    const char* rb = y1 + arow * 256;
                    int swz = (arow & 7) << 4;
                    f32x4 acc = (f32x4){0.f, 0.f, 0.f, 0.f};
#pragma unroll
                    for (int ks = 0; ks < 4; ++ks){
                        s16x8 a = *(const s16x8*)(rb + (((ks * 32 + kgrp * 8) * 2) ^ swz));
                        acc = __builtin_amdgcn_mfma_f32_16x16x32_bf16(a, bfr[ks], acc, 0, 0, 0);
                    }
                    a6[mt] = acc;
                }
                float cs = 0.f;
#pragma unroll
                for (int mt = 0; mt < 6; ++mt)
#pragma unroll
                    for (int i = 0; i < 4; ++i){
                        int row = mt * 16 + kgrp * 4 + i;
                        if (row < EPN) cs += eluf(a6[mt][i] + b2v);
                    }
                cs += __shfl_xor(cs, 16); cs += __shfl_xor(cs, 32);
                if (l < 16) gL[r12 * DM + wv * 16 + l] = cs * (1.f / 95.f);
                __syncthreads();
            }
        } else {
            // ---------- final stage: fW2 (padded N=16), hi+lo ----------
            s16x8 fh[4], fl4[4];
#pragma unroll
            for (int ks = 0; ks < 4; ++ks){
                fh[ks]  = *frag(whi + 18 * 16384, 0, ks, l);
                fl4[ks] = *frag(wlo + 18 * 16384, 0, ks, l);
            }
            float fbv = (l15 < 6) ? fb2[l15] : 0.f;
            __syncthreads();
            for (int r12 = 0; r12 < 12; ++r12){
                int r = r0 + r12;
                buildY1(r, r12);
                __syncthreads();
                if (wv < 6){
                    int arow = wv * 16 + l15;
                    const char* rb = y1 + arow * 256;
                    int swz = (l15 & 7) << 4;
                    s16x8 a[4];
#pragma unroll
                    for (int ks = 0; ks < 4; ++ks)
                        a[ks] = *(const s16x8*)(rb + (((ks * 32 + kgrp * 8) * 2) ^ swz));
                    f32x4 acc = (f32x4){fbv, fbv, fbv, fbv};
#pragma unroll
                    for (int ks = 0; ks < 4; ++ks)
                        acc = __builtin_amdgcn_mfma_f32_16x16x32_bf16(a[ks], fh[ks], acc, 0, 0, 0);
#pragma unroll
                    for (int ks = 0; ks < 4; ++ks)
                        acc = __builtin_amdgcn_mfma_f32_16x16x32_bf16(a[ks], fl4[ks], acc, 0, 0, 0);
                    if (l15 < 6){
                        float* ob = out + ((size_t)bb * (LN * EPN) + (size_t)r * EPN) * 6;
#pragma unroll
                        for (int i = 0; i < 4; ++i){
                            int row = wv * 16 + kgrp * 4 + i;
                            if (row < EPN) ob[(size_t)row * 6 + l15] = acc[i];
                        }
                    }
                }
                __syncthreads();
            }
        }
    }
}

extern "C" void kernel_launch(void* const* d_in, const int* in_sizes, int n_in,
                              void* d_out, int out_size, void* d_ws, size_t ws_size,
                              hipStream_t stream) {
    const float* inputs = (const float*)d_in[0];
    const float* W0a = (const float*)d_in[3];
    const float* b0a = (const float*)d_in[4];
    const float* W0b = (const float*)d_in[5];
    const float* b0b = (const float*)d_in[6];
    const float* eW1 = (const float*)d_in[7];
    const float* eb1 = (const float*)d_in[8];
    const float* eW2 = (const float*)d_in[9];
    const float* eb2 = (const float*)d_in[10];
    const float* nW1 = (const float*)d_in[11];
    const float* nb1 = (const float*)d_in[12];
    const float* nW2 = (const float*)d_in[13];
    const float* nb2 = (const float*)d_in[14];
    const float* fW1 = (const float*)d_in[15];
    const float* fb1 = (const float*)d_in[16];
    const float* fW2 = (const float*)d_in[17];
    const float* fb2 = (const float*)d_in[18];
    float* out = (float*)d_out;

    unsigned short* whi = (unsigned short*)d_ws;            // 19 x 16384 bf16 hi
    unsigned short* wlo = whi + 19 * 16384;                 // 19 x 16384 bf16 lo
    float* hsbuf = (float*)(wlo + 19 * 16384);              // 2 x (32*96*128) f32 (round parity)
    unsigned* ctr = (unsigned*)(hsbuf + 2 * BN * LN * DM);  // 32 batches x 32 u32 (padded)

    SrcTab tab;
    tab.p[0] = eW2;          tab.p[1] = eW2 + 16384;  tab.p[2] = eW2 + 32768;
    tab.p[3] = W0b;
    tab.p[4] = eW1;          tab.p[5] = eW1 + 16384;
    tab.p[6] = nW1;          tab.p[7] = nW2;          tab.p[8] = eW1 + 32768;  tab.p[9]  = eW1 + 49152;
    tab.p[10] = nW1 + 16384; tab.p[11] = nW2 + 16384; tab.p[12] = eW1 + 65536; tab.p[13] = eW1 + 81920;
    tab.p[14] = nW1 + 32768; tab.p[15] = nW2 + 32768; tab.p[16] = fW1;         tab.p[17] = fW1 + 16384;
    tab.p[18] = fW2;

    hipMemsetAsync(ctr, 0, 32 * 32 * sizeof(unsigned), stream);
    conv_pack_kernel<<<152, 256, 0, stream>>>(tab, whi, wlo);
    gnn_persistent<<<256, 512, 0, stream>>>(inputs, W0a, b0a, b0b, nb1, nb2, eb1, eb2, fb1, fb2,
                                            whi, wlo, hsbuf, ctr, out);
}